// Round 1
// baseline (723.554 us; speedup 1.0000x reference)
//
#include <hip/hip_runtime.h>

#define N_NODES 100000
#define N_EDGES 1600000
#define DIM 64

static constexpr float BN_EPS = 1e-5f;
static constexpr float SLOPE = 0.3f;

// ---------------------------------------------------------------------------
// Pass 1: per-node transforms.
//   A[n] = feat[n] @ (W1 - W2)^T + b      (W1 = W[:, :64], W2 = W[:, 64:])
//   B[n] = feat[n] @ W2^T
// so that per edge:  m_e = A[dst_e] + B[src_e]
// ---------------------------------------------------------------------------
__global__ __launch_bounds__(256) void node_transform_kernel(
    const float* __restrict__ feat, const float* __restrict__ W,
    const float* __restrict__ bias, float* __restrict__ A,
    float* __restrict__ Bm) {
  // LDS weights laid out [k][c]: lane==c reads stride-4B -> 2-way alias (free)
  __shared__ float Wa[64][64];
  __shared__ float Wb[64][64];
  int t = threadIdx.x;
  for (int i = t; i < 64 * 64; i += 256) {
    int c = i >> 6, k = i & 63;
    float w1 = W[c * 128 + k];
    float w2 = W[c * 128 + 64 + k];
    Wa[k][c] = w1 - w2;
    Wb[k][c] = w2;
  }
  __syncthreads();

  int lane = t & 63;
  int wv = t >> 6;
  int gwave = blockIdx.x * 4 + wv;
  int nwaves = gridDim.x * 4;
  float bc = bias[lane];

  for (int n = gwave; n < N_NODES; n += nwaves) {
    float v = feat[n * 64 + lane];  // coalesced row load, one element/lane
    float a = bc;
    float bb = 0.f;
#pragma unroll
    for (int k = 0; k < 64; ++k) {
      float fv = __shfl(v, k, 64);  // broadcast f[n][k] register-only
      a += fv * Wa[k][lane];
      bb += fv * Wb[k][lane];
    }
    A[n * 64 + lane] = a;
    Bm[n * 64 + lane] = bb;
  }
}

// ---------------------------------------------------------------------------
// Pass 2: batch-norm statistics over all E edges (sum and sum-of-squares per
// channel). Lane = channel; wave iterates edges; block-reduce; atomics once.
// ---------------------------------------------------------------------------
__global__ __launch_bounds__(256) void edge_stats_kernel(
    const int* __restrict__ ei, const float* __restrict__ A,
    const float* __restrict__ Bm, float* __restrict__ sums) {
  const int* __restrict__ src = ei;
  const int* __restrict__ dst = ei + N_EDGES;
  int lane = threadIdx.x & 63;
  int wv = threadIdx.x >> 6;
  int gwave = blockIdx.x * 4 + wv;
  int nwaves = gridDim.x * 4;

  float s = 0.f, sq = 0.f;
  for (int e = gwave; e < N_EDGES; e += nwaves) {
    int d = dst[e];  // wave-uniform broadcast load
    int sr = src[e];
    float m = A[d * 64 + lane] + Bm[sr * 64 + lane];
    s += m;
    sq += m * m;
  }

  __shared__ float ls[4][64];
  __shared__ float lq[4][64];
  ls[wv][lane] = s;
  lq[wv][lane] = sq;
  __syncthreads();
  if (wv == 0) {
    float ts = ls[0][lane] + ls[1][lane] + ls[2][lane] + ls[3][lane];
    float tq = lq[0][lane] + lq[1][lane] + lq[2][lane] + lq[3][lane];
    atomicAdd(&sums[lane], ts);
    atomicAdd(&sums[64 + lane], tq);
  }
}

// ---------------------------------------------------------------------------
// Pass 3: fold BN stats + affine into per-channel scale/shift.
// ---------------------------------------------------------------------------
__global__ __launch_bounds__(64) void bn_params_kernel(
    const float* __restrict__ sums, const float* __restrict__ gamma,
    const float* __restrict__ beta, float* __restrict__ ss) {
  int c = threadIdx.x;
  const float invE = 1.0f / (float)N_EDGES;
  float mu = sums[c] * invE;
  float var = sums[64 + c] * invE - mu * mu;
  float rs = rsqrtf(var + BN_EPS);
  float sc = gamma[c] * rs;
  ss[c] = sc;
  ss[64 + c] = beta[c] - mu * sc;
}

// ---------------------------------------------------------------------------
// Pass 4: per-edge normalize + LeakyReLU + scatter-add into out, count dst.
// ---------------------------------------------------------------------------
__global__ __launch_bounds__(256) void edge_aggregate_kernel(
    const int* __restrict__ ei, const float* __restrict__ A,
    const float* __restrict__ Bm, const float* __restrict__ ss,
    float* __restrict__ out, float* __restrict__ cnt) {
  const int* __restrict__ src = ei;
  const int* __restrict__ dst = ei + N_EDGES;
  int lane = threadIdx.x & 63;
  int wv = threadIdx.x >> 6;
  int gwave = blockIdx.x * 4 + wv;
  int nwaves = gridDim.x * 4;

  float sc = ss[lane];
  float sh = ss[64 + lane];

  for (int e = gwave; e < N_EDGES; e += nwaves) {
    int d = dst[e];
    int sr = src[e];
    float m = A[d * 64 + lane] + Bm[sr * 64 + lane];
    float y = m * sc + sh;
    y = (y >= 0.f) ? y : SLOPE * y;
    atomicAdd(&out[d * 64 + lane], y);
    if (lane == 0) atomicAdd(&cnt[d], 1.0f);
  }
}

// ---------------------------------------------------------------------------
// Pass 5: divide by max(count, 1).
// ---------------------------------------------------------------------------
__global__ __launch_bounds__(256) void finalize_kernel(
    float* __restrict__ out, const float* __restrict__ cnt) {
  int i = blockIdx.x * 256 + threadIdx.x;
  if (i < N_NODES * 64) {
    float c = cnt[i >> 6];
    out[i] = out[i] * (1.0f / fmaxf(c, 1.0f));
  }
}

extern "C" void kernel_launch(void* const* d_in, const int* in_sizes, int n_in,
                              void* d_out, int out_size, void* d_ws,
                              size_t ws_size, hipStream_t stream) {
  const float* feat = (const float*)d_in[0];
  const int* ei = (const int*)d_in[1];
  const float* W = (const float*)d_in[2];
  const float* b = (const float*)d_in[3];
  const float* gamma = (const float*)d_in[4];
  const float* beta = (const float*)d_in[5];
  float* out = (float*)d_out;

  // Workspace layout (floats)
  float* A = (float*)d_ws;                  // 6,400,000
  float* Bm = A + (size_t)N_NODES * 64;     // 6,400,000
  float* sums = Bm + (size_t)N_NODES * 64;  // 128
  float* ss = sums + 128;                   // 128
  float* cnt = ss + 128;                    // 100,000

  // Zero accumulators (harness poisons d_out/d_ws once; we must re-zero
  // every call).
  hipMemsetAsync(out, 0, (size_t)N_NODES * 64 * sizeof(float), stream);
  hipMemsetAsync(sums, 0, 128 * sizeof(float), stream);
  hipMemsetAsync(cnt, 0, (size_t)N_NODES * sizeof(float), stream);

  node_transform_kernel<<<1024, 256, 0, stream>>>(feat, W, b, A, Bm);
  edge_stats_kernel<<<2048, 256, 0, stream>>>(ei, A, Bm, sums);
  bn_params_kernel<<<1, 64, 0, stream>>>(sums, gamma, beta, ss);
  edge_aggregate_kernel<<<2048, 256, 0, stream>>>(ei, A, Bm, ss, out, cnt);
  finalize_kernel<<<(N_NODES * 64 + 255) / 256, 256, 0, stream>>>(out, cnt);
}